// Round 1
// baseline (138.571 us; speedup 1.0000x reference)
//
#include <hip/hip_runtime.h>
#include <hip/hip_bf16.h>

// Problem constants
#define IN_F   2048
#define N_CON  64
#define EMB    128
#define BATCH  8192

// Output layout (f32 elements): c_emb | c_pred | c_int | emb
#define CEMB_OFF  0
#define CPRED_OFF 67108864   // 8192*64*128
#define CINT_OFF  67633152   // + 8192*64
#define EMB_OFF   68157440   // + 8192*64

typedef __attribute__((ext_vector_type(4))) float f32x4;
typedef __attribute__((ext_vector_type(8))) short short8;
typedef __attribute__((ext_vector_type(4))) short short4v;

#define MFMA16(A,B,C) __builtin_amdgcn_mfma_f32_16x16x32_bf16((A),(B),(C),0,0,0)

__device__ __forceinline__ short f2bf(float f) {
  unsigned u = __float_as_uint(f);
  u += 0x7FFFu + ((u >> 16) & 1u);   // round-to-nearest-even
  return (short)(u >> 16);
}

__device__ __forceinline__ void gload_lds16(const void* g, void* l) {
  __builtin_amdgcn_global_load_lds(
      (const __attribute__((address_space(1))) unsigned*)g,
      (__attribute__((address_space(3))) unsigned*)l, 16, 0, 0);
}

// ---------------- kernel 0: f32 -> bf16 convert (We, Wc) ----------------
__global__ void conv_bf16_kernel(const float* __restrict__ src,
                                 short* __restrict__ dst, int n4) {
  int i = blockIdx.x * blockDim.x + threadIdx.x;
  if (i < n4) {
    f32x4 v = *(const f32x4*)(src + (size_t)i * 4);
    short4v o;
    o.x = f2bf(v.x); o.y = f2bf(v.y); o.z = f2bf(v.z); o.w = f2bf(v.w);
    *(short4v*)(dst + (size_t)i * 4) = o;
  }
}

// ---------------- kernel 1: emb = leaky(x @ We^T + be) ----------------
// BM=32, N=128 (full), K-loop BK=128. 256 threads (4 waves), grid 256.
__global__ __launch_bounds__(256, 4)
void gemm1_kernel(const float* __restrict__ x,
                  const short* __restrict__ we_bf,   // [128][2048] bf16
                  const float* __restrict__ be,
                  float* __restrict__ out_emb,       // [8192][128] f32
                  short* __restrict__ emb_bf) {      // [8192][128] bf16
  __shared__ short As[32 * 128];    // 8 KB, XOR-swizzled
  __shared__ short Bs[128 * 128];   // 32 KB, XOR-swizzled

  const int t = threadIdx.x;
  const int w = t >> 6, l = t & 63;
  const int row0 = blockIdx.x * 32;

  f32x4 acc[2][2];
#pragma unroll
  for (int i = 0; i < 2; ++i)
#pragma unroll
    for (int j = 0; j < 2; ++j) acc[i][j] = (f32x4){0.f, 0.f, 0.f, 0.f};

  // A staging map: thread t -> row ar (0..31), 16-elem segment as (0..7)
  const int ar = t >> 3;
  const int as = t & 7;
  const float* xrow = x + (size_t)(row0 + ar) * IN_F + as * 16;

  // B staging map (global_load_lds, pre-swizzled source)
  const int brl = t >> 4;      // 0..15 row-within-issue
  const int bseg = l & 15;     // 16B granule within 128-elem row slice

  for (int kt = 0; kt < 16; ++kt) {
    const int k0 = kt * 128;
    // ---- stage A: f32 -> bf16 through regs, swizzled ds_write ----
#pragma unroll
    for (int h = 0; h < 2; ++h) {
      f32x4 v0 = *(const f32x4*)(xrow + k0 + h * 8);
      f32x4 v1 = *(const f32x4*)(xrow + k0 + h * 8 + 4);
      short8 o;
      o[0] = f2bf(v0.x); o[1] = f2bf(v0.y); o[2] = f2bf(v0.z); o[3] = f2bf(v0.w);
      o[4] = f2bf(v1.x); o[5] = f2bf(v1.y); o[6] = f2bf(v1.z); o[7] = f2bf(v1.w);
      int col = (as * 16 + h * 8) ^ ((ar & 7) << 3);
      *(short8*)&As[ar * 128 + col] = o;
    }
    // ---- stage B: 8 issues x (256 thr * 16B) = 32 KB ----
#pragma unroll
    for (int i = 0; i < 8; ++i) {
      int n = i * 16 + brl;
      const short* src = we_bf + (size_t)n * IN_F + k0 + ((bseg ^ (n & 7)) * 8);
      gload_lds16(src, &Bs[i * 2048 + w * 512]);
    }
    __syncthreads();
    // ---- MFMA: wave w owns cols w*32..w*32+31 ----
#pragma unroll
    for (int ks = 0; ks < 4; ++ks) {
      int kcol = ks * 32 + ((l >> 4) << 3);
      int r0 = l & 15, r1 = 16 + (l & 15);
      short8 a0 = *(const short8*)&As[r0 * 128 + (kcol ^ ((r0 & 7) << 3))];
      short8 a1 = *(const short8*)&As[r1 * 128 + (kcol ^ ((r1 & 7) << 3))];
      int n0 = w * 32 + (l & 15), n1 = w * 32 + 16 + (l & 15);
      short8 b0 = *(const short8*)&Bs[n0 * 128 + (kcol ^ ((n0 & 7) << 3))];
      short8 b1 = *(const short8*)&Bs[n1 * 128 + (kcol ^ ((n1 & 7) << 3))];
      acc[0][0] = MFMA16(a0, b0, acc[0][0]);
      acc[1][0] = MFMA16(a1, b0, acc[1][0]);
      acc[0][1] = MFMA16(a0, b1, acc[0][1]);
      acc[1][1] = MFMA16(a1, b1, acc[1][1]);
    }
    __syncthreads();
  }

  // epilogue: + be, leaky, store f32 + bf16
#pragma unroll
  for (int nf = 0; nf < 2; ++nf) {
    int e = w * 32 + nf * 16 + (l & 15);
    float bev = be[e];
#pragma unroll
    for (int mf = 0; mf < 2; ++mf) {
#pragma unroll
      for (int r = 0; r < 4; ++r) {
        int b = row0 + mf * 16 + ((l >> 4) << 2) + r;
        float v = acc[mf][nf][r] + bev;
        v = v >= 0.f ? v : 0.01f * v;
        out_emb[(size_t)b * EMB + e] = v;
        emb_bf[(size_t)b * EMB + e] = f2bf(v);
      }
    }
  }
}

// ---------------- kernel 2: fused context/gate/c_emb ----------------
// Block = (256 batch rows, 1 concept). 512 threads = 8 waves, each wave:
// 32 rows x 256 cols, acc[2][16]. K=128 done in one shot (no K-tiling).
__global__ __launch_bounds__(512, 2)
void gemm2_kernel(const short* __restrict__ emb_bf,  // [8192][128] bf16
                  const short* __restrict__ wc_bf,   // [64][256][128] bf16
                  const float* __restrict__ bc,      // [64][256]
                  const float* __restrict__ wp,      // [256]
                  const float* __restrict__ bp,      // [1]
                  float* __restrict__ out) {
  __shared__ short As[256 * 128];   // 64 KB
  __shared__ short Bs[256 * 128];   // 64 KB

  const int t = threadIdx.x;
  const int w = t >> 6, l = t & 63;
  const int kc = blockIdx.x & 63;          // concept
  const int mbase = (blockIdx.x >> 6) * 256;

  // per-lane epilogue constants (col = nf*16 + (l&15))
  float wph[16], bcv[16];
#pragma unroll
  for (int nf = 0; nf < 16; ++nf) {
    wph[nf] = wp[nf * 16 + (l & 15)];
    bcv[nf] = bc[kc * 256 + nf * 16 + (l & 15)];
  }
  const float bp0 = bp[0];

  // ---- stage A (emb rows) and B (Wc[kc]) via global_load_lds ----
  const int rl = t >> 4;       // 0..31 row-within-issue
  const int seg = l & 15;
#pragma unroll
  for (int i = 0; i < 8; ++i) {
    int rA = i * 32 + rl;
    gload_lds16(emb_bf + (size_t)(mbase + rA) * 128 + ((seg ^ (rA & 7)) * 8),
                &As[i * 4096 + w * 512]);
  }
#pragma unroll
  for (int i = 0; i < 8; ++i) {
    int rB = i * 32 + rl;
    gload_lds16(wc_bf + (size_t)kc * 32768 + (size_t)rB * 128 + ((seg ^ (rB & 7)) * 8),
                &Bs[i * 4096 + w * 512]);
  }
  __syncthreads();

  f32x4 acc[2][16];
#pragma unroll
  for (int i = 0; i < 2; ++i)
#pragma unroll
    for (int j = 0; j < 16; ++j) acc[i][j] = (f32x4){0.f, 0.f, 0.f, 0.f};

  const int wr = w * 32;
#pragma unroll
  for (int ks = 0; ks < 4; ++ks) {
    int kcol = ks * 32 + ((l >> 4) << 3);
    int r0 = wr + (l & 15), r1 = wr + 16 + (l & 15);
    short8 a0 = *(const short8*)&As[r0 * 128 + (kcol ^ ((r0 & 7) << 3))];
    short8 a1 = *(const short8*)&As[r1 * 128 + (kcol ^ ((r1 & 7) << 3))];
#pragma unroll
    for (int nf = 0; nf < 16; ++nf) {
      int n = nf * 16 + (l & 15);
      short8 b = *(const short8*)&Bs[n * 128 + (kcol ^ ((n & 7) << 3))];
      acc[0][nf] = MFMA16(a0, b, acc[0][nf]);
      acc[1][nf] = MFMA16(a1, b, acc[1][nf]);
    }
  }

  // ---- epilogue: leaky, wp-dot (shfl over 16 lanes), sigmoid, gate ----
  float g[2][4];
#pragma unroll
  for (int mf = 0; mf < 2; ++mf) {
    f32x4 p = (f32x4){0.f, 0.f, 0.f, 0.f};
#pragma unroll
    for (int nf = 0; nf < 16; ++nf) {
#pragma unroll
      for (int r = 0; r < 4; ++r) {
        float v = acc[mf][nf][r] + bcv[nf];
        v = v >= 0.f ? v : 0.01f * v;
        acc[mf][nf][r] = v;             // acc now holds context
        p[r] += v * wph[nf];
      }
    }
#pragma unroll
    for (int r = 0; r < 4; ++r) {
      float s = p[r];
      s += __shfl_xor(s, 1);
      s += __shfl_xor(s, 2);
      s += __shfl_xor(s, 4);
      s += __shfl_xor(s, 8);
      g[mf][r] = 1.f / (1.f + __expf(-(s + bp0)));
    }
  }

#pragma unroll
  for (int mf = 0; mf < 2; ++mf) {
#pragma unroll
    for (int r = 0; r < 4; ++r) {
      int brow = mbase + wr + mf * 16 + ((l >> 4) << 2) + r;
      float gg = g[mf][r];
      if ((l & 15) == 0) {
        out[CPRED_OFF + (size_t)brow * 64 + kc] = gg;
        out[CINT_OFF + (size_t)brow * 64 + kc] = gg;
      }
#pragma unroll
      for (int nf = 0; nf < 8; ++nf) {
        float v = acc[mf][nf][r] * gg + acc[mf][nf + 8][r] * (1.f - gg);
        out[(size_t)brow * 8192 + kc * 128 + nf * 16 + (l & 15)] = v;
      }
    }
  }
}

extern "C" void kernel_launch(void* const* d_in, const int* in_sizes, int n_in,
                              void* d_out, int out_size, void* d_ws, size_t ws_size,
                              hipStream_t stream) {
  (void)in_sizes; (void)n_in; (void)out_size; (void)ws_size;
  const float* x  = (const float*)d_in[0];
  const float* We = (const float*)d_in[1];
  const float* be = (const float*)d_in[2];
  const float* Wc = (const float*)d_in[3];
  const float* bc = (const float*)d_in[4];
  const float* wp = (const float*)d_in[5];
  const float* bp = (const float*)d_in[6];
  float* out = (float*)d_out;

  // ws layout: We_bf16 (512KB) | Wc_bf16 (4MB) | emb_bf16 (2MB)
  short* we_bf  = (short*)d_ws;
  short* wc_bf  = we_bf + 262144;
  short* emb_bf = wc_bf + 2097152;

  conv_bf16_kernel<<<256, 256, 0, stream>>>(We, we_bf, 65536);
  conv_bf16_kernel<<<2048, 256, 0, stream>>>(Wc, wc_bf, 524288);
  gemm1_kernel<<<256, 256, 0, stream>>>(x, we_bf, be, out + EMB_OFF, emb_bf);
  gemm2_kernel<<<2048, 512, 0, stream>>>(emb_bf, wc_bf, bc, wp, bp, out);
}

// Round 2
// 136.450 us; speedup vs baseline: 1.0155x; 1.0155x over previous
//
#include <hip/hip_runtime.h>
#include <hip/hip_bf16.h>

// Problem constants
#define IN_F   2048
#define N_CON  64
#define EMB    128
#define BATCH  8192

// Output layout (f32 elements): c_emb | c_pred | c_int | emb
#define CEMB_OFF  0
#define CPRED_OFF 67108864   // 8192*64*128
#define CINT_OFF  67633152   // + 8192*64
#define EMB_OFF   68157440   // + 8192*64

typedef __attribute__((ext_vector_type(4))) float f32x4;
typedef __attribute__((ext_vector_type(8))) short short8;
typedef __attribute__((ext_vector_type(4))) short short4v;

#define MFMA16(A,B,C) __builtin_amdgcn_mfma_f32_16x16x32_bf16((A),(B),(C),0,0,0)

__device__ __forceinline__ short f2bf(float f) {
  unsigned u = __float_as_uint(f);
  u += 0x7FFFu + ((u >> 16) & 1u);   // round-to-nearest-even
  return (short)(u >> 16);
}

__device__ __forceinline__ void gload_lds16(const void* g, void* l) {
  __builtin_amdgcn_global_load_lds(
      (const __attribute__((address_space(1))) unsigned*)g,
      (__attribute__((address_space(3))) unsigned*)l, 16, 0, 0);
}

// ---------------- kernel 0: f32 -> bf16 convert (We + Wc merged) ----------------
__global__ void conv2_kernel(const float* __restrict__ a, short* __restrict__ da, int n4a,
                             const float* __restrict__ b, short* __restrict__ db, int n4b) {
  int i = blockIdx.x * blockDim.x + threadIdx.x;
  const float* s; short* d; int j;
  if (i < n4a)            { s = a; d = da; j = i; }
  else if (i < n4a + n4b) { s = b; d = db; j = i - n4a; }
  else return;
  f32x4 v = *(const f32x4*)(s + (size_t)j * 4);
  short4v o;
  o.x = f2bf(v.x); o.y = f2bf(v.y); o.z = f2bf(v.z); o.w = f2bf(v.w);
  *(short4v*)(d + (size_t)j * 4) = o;
}

// ---------------- kernel 1: emb = leaky(x @ We^T + be) ----------------
// BM=32, N=128 (full), K-loop BK=128. 256 threads (4 waves), grid 256.
__global__ __launch_bounds__(256, 4)
void gemm1_kernel(const float* __restrict__ x,
                  const short* __restrict__ we_bf,   // [128][2048] bf16
                  const float* __restrict__ be,
                  float* __restrict__ out_emb,       // [8192][128] f32
                  short* __restrict__ emb_bf) {      // [8192][128] bf16
  __shared__ short As[32 * 128];    // 8 KB, XOR-swizzled
  __shared__ short Bs[128 * 128];   // 32 KB, XOR-swizzled

  const int t = threadIdx.x;
  const int w = t >> 6, l = t & 63;
  const int row0 = blockIdx.x * 32;

  f32x4 acc[2][2];
#pragma unroll
  for (int i = 0; i < 2; ++i)
#pragma unroll
    for (int j = 0; j < 2; ++j) acc[i][j] = (f32x4){0.f, 0.f, 0.f, 0.f};

  // A staging map: thread t -> row ar (0..31), 16-elem segment as (0..7)
  const int ar = t >> 3;
  const int as = t & 7;
  const float* xrow = x + (size_t)(row0 + ar) * IN_F + as * 16;

  // B staging map (global_load_lds, pre-swizzled source)
  const int brl = t >> 4;      // 0..15 row-within-issue
  const int bseg = l & 15;     // 16B granule within 128-elem row slice

  for (int kt = 0; kt < 16; ++kt) {
    const int k0 = kt * 128;
    // ---- stage A: f32 -> bf16 through regs, swizzled ds_write ----
#pragma unroll
    for (int h = 0; h < 2; ++h) {
      f32x4 v0 = *(const f32x4*)(xrow + k0 + h * 8);
      f32x4 v1 = *(const f32x4*)(xrow + k0 + h * 8 + 4);
      short8 o;
      o[0] = f2bf(v0.x); o[1] = f2bf(v0.y); o[2] = f2bf(v0.z); o[3] = f2bf(v0.w);
      o[4] = f2bf(v1.x); o[5] = f2bf(v1.y); o[6] = f2bf(v1.z); o[7] = f2bf(v1.w);
      int col = (as * 16 + h * 8) ^ ((ar & 7) << 3);
      *(short8*)&As[ar * 128 + col] = o;
    }
    // ---- stage B: 8 issues x (256 thr * 16B) = 32 KB ----
#pragma unroll
    for (int i = 0; i < 8; ++i) {
      int n = i * 16 + brl;
      const short* src = we_bf + (size_t)n * IN_F + k0 + ((bseg ^ (n & 7)) * 8);
      gload_lds16(src, &Bs[i * 2048 + w * 512]);
    }
    __syncthreads();
    // ---- MFMA: wave w owns cols w*32..w*32+31 ----
#pragma unroll
    for (int ks = 0; ks < 4; ++ks) {
      int kcol = ks * 32 + ((l >> 4) << 3);
      int r0 = l & 15, r1 = 16 + (l & 15);
      short8 a0 = *(const short8*)&As[r0 * 128 + (kcol ^ ((r0 & 7) << 3))];
      short8 a1 = *(const short8*)&As[r1 * 128 + (kcol ^ ((r1 & 7) << 3))];
      int n0 = w * 32 + (l & 15), n1 = w * 32 + 16 + (l & 15);
      short8 b0 = *(const short8*)&Bs[n0 * 128 + (kcol ^ ((n0 & 7) << 3))];
      short8 b1 = *(const short8*)&Bs[n1 * 128 + (kcol ^ ((n1 & 7) << 3))];
      acc[0][0] = MFMA16(a0, b0, acc[0][0]);
      acc[1][0] = MFMA16(a1, b0, acc[1][0]);
      acc[0][1] = MFMA16(a0, b1, acc[0][1]);
      acc[1][1] = MFMA16(a1, b1, acc[1][1]);
    }
    __syncthreads();
  }

  // epilogue: + be, leaky, store f32 + bf16
#pragma unroll
  for (int nf = 0; nf < 2; ++nf) {
    int e = w * 32 + nf * 16 + (l & 15);
    float bev = be[e];
#pragma unroll
    for (int mf = 0; mf < 2; ++mf) {
#pragma unroll
      for (int r = 0; r < 4; ++r) {
        int b = row0 + mf * 16 + ((l >> 4) << 2) + r;
        float v = acc[mf][nf][r] + bev;
        v = v >= 0.f ? v : 0.01f * v;
        out_emb[(size_t)b * EMB + e] = v;
        emb_bf[(size_t)b * EMB + e] = f2bf(v);
      }
    }
  }
}

// ---------------- kernel 2: fused context/gate/c_emb ----------------
// Block = (256 batch rows, 1 concept). 512 threads = 8 waves, each wave:
// 32 rows x 256 cols, acc[2][16]. K=128 done in one shot (no K-tiling).
// Gate values go to ws_pred[64][8192] (block-contiguous, full-line writes);
// the [8192][64] out layout is produced by pred_tr_kernel (avoids cross-XCD
// false sharing on 4-B scattered stores).
__global__ __launch_bounds__(512, 2)
void gemm2_kernel(const short* __restrict__ emb_bf,  // [8192][128] bf16
                  const short* __restrict__ wc_bf,   // [64][256][128] bf16
                  const float* __restrict__ bc,      // [64][256]
                  const float* __restrict__ wp,      // [256]
                  const float* __restrict__ bp,      // [1]
                  float* __restrict__ ws_pred,       // [64][8192]
                  float* __restrict__ out) {
  __shared__ short As[256 * 128];   // 64 KB
  __shared__ short Bs[256 * 128];   // 64 KB

  const int t = threadIdx.x;
  const int w = t >> 6, l = t & 63;
  const int kc = blockIdx.x & 63;          // concept
  const int mbase = (blockIdx.x >> 6) * 256;

  // per-lane epilogue constants (col = nf*16 + (l&15))
  float wph[16], bcv[16];
#pragma unroll
  for (int nf = 0; nf < 16; ++nf) {
    wph[nf] = wp[nf * 16 + (l & 15)];
    bcv[nf] = bc[kc * 256 + nf * 16 + (l & 15)];
  }
  const float bp0 = bp[0];

  // ---- stage A (emb rows) and B (Wc[kc]) via global_load_lds ----
  const int rl = t >> 4;       // 0..31 row-within-issue
  const int seg = l & 15;
#pragma unroll
  for (int i = 0; i < 8; ++i) {
    int rA = i * 32 + rl;
    gload_lds16(emb_bf + (size_t)(mbase + rA) * 128 + ((seg ^ (rA & 7)) * 8),
                &As[i * 4096 + w * 512]);
  }
#pragma unroll
  for (int i = 0; i < 8; ++i) {
    int rB = i * 32 + rl;
    gload_lds16(wc_bf + (size_t)kc * 32768 + (size_t)rB * 128 + ((seg ^ (rB & 7)) * 8),
                &Bs[i * 4096 + w * 512]);
  }
  __syncthreads();

  f32x4 acc[2][16];
#pragma unroll
  for (int i = 0; i < 2; ++i)
#pragma unroll
    for (int j = 0; j < 16; ++j) acc[i][j] = (f32x4){0.f, 0.f, 0.f, 0.f};

  const int wr = w * 32;
#pragma unroll
  for (int ks = 0; ks < 4; ++ks) {
    int kcol = ks * 32 + ((l >> 4) << 3);
    int r0 = wr + (l & 15), r1 = wr + 16 + (l & 15);
    short8 a0 = *(const short8*)&As[r0 * 128 + (kcol ^ ((r0 & 7) << 3))];
    short8 a1 = *(const short8*)&As[r1 * 128 + (kcol ^ ((r1 & 7) << 3))];
#pragma unroll
    for (int nf = 0; nf < 16; ++nf) {
      int n = nf * 16 + (l & 15);
      short8 b = *(const short8*)&Bs[n * 128 + (kcol ^ ((n & 7) << 3))];
      acc[0][nf] = MFMA16(a0, b, acc[0][nf]);
      acc[1][nf] = MFMA16(a1, b, acc[1][nf]);
    }
  }

  // ---- epilogue: leaky, wp-dot (shfl over 16 lanes), sigmoid, gate ----
  float g[2][4];
#pragma unroll
  for (int mf = 0; mf < 2; ++mf) {
    f32x4 p = (f32x4){0.f, 0.f, 0.f, 0.f};
#pragma unroll
    for (int nf = 0; nf < 16; ++nf) {
#pragma unroll
      for (int r = 0; r < 4; ++r) {
        float v = acc[mf][nf][r] + bcv[nf];
        v = v >= 0.f ? v : 0.01f * v;
        acc[mf][nf][r] = v;             // acc now holds context
        p[r] += v * wph[nf];
      }
    }
#pragma unroll
    for (int r = 0; r < 4; ++r) {
      float s = p[r];
      s += __shfl_xor(s, 1);
      s += __shfl_xor(s, 2);
      s += __shfl_xor(s, 4);
      s += __shfl_xor(s, 8);
      g[mf][r] = 1.f / (1.f + __expf(-(s + bp0)));
    }
  }

  // gate values -> ws_pred[kc][brow], 16-B stores, block-contiguous region
  if ((l & 15) == 0) {
#pragma unroll
    for (int mf = 0; mf < 2; ++mf) {
      f32x4 gv;
      gv.x = g[mf][0]; gv.y = g[mf][1]; gv.z = g[mf][2]; gv.w = g[mf][3];
      *(f32x4*)&ws_pred[(size_t)kc * 8192 + mbase + wr + mf * 16 + ((l >> 4) << 2)] = gv;
    }
  }

#pragma unroll
  for (int mf = 0; mf < 2; ++mf) {
#pragma unroll
    for (int r = 0; r < 4; ++r) {
      int brow = mbase + wr + mf * 16 + ((l >> 4) << 2) + r;
      float gg = g[mf][r];
#pragma unroll
      for (int nf = 0; nf < 8; ++nf) {
        float v = acc[mf][nf][r] * gg + acc[mf][nf + 8][r] * (1.f - gg);
        out[(size_t)brow * 8192 + kc * 128 + nf * 16 + (l & 15)] = v;
      }
    }
  }
}

// ---------------- kernel 3: transpose ws_pred -> c_pred, c_int ----------------
// Tile: 64 kc x 64 rows per block. Grid 128.
__global__ __launch_bounds__(256)
void pred_tr_kernel(const float* __restrict__ ws_pred, float* __restrict__ out) {
  __shared__ float T[64][65];
  const int t = threadIdx.x;
  const int b0 = blockIdx.x * 64;

  // read phase: thread t -> kc = t>>2, 16 consecutive b
  {
    int kc = t >> 2;
    int j0 = (t & 3) * 16;
    const float* src = ws_pred + (size_t)kc * 8192 + b0 + j0;
#pragma unroll
    for (int i = 0; i < 4; ++i) {
      f32x4 v = *(const f32x4*)(src + i * 4);
      T[kc][j0 + i * 4 + 0] = v.x;
      T[kc][j0 + i * 4 + 1] = v.y;
      T[kc][j0 + i * 4 + 2] = v.z;
      T[kc][j0 + i * 4 + 3] = v.w;
    }
  }
  __syncthreads();
  // write phase: thread t -> row b0+(t&63), kc range (t>>6)*16..+15
  {
    int bl = t & 63;
    int kq = (t >> 6) * 16;
#pragma unroll
    for (int i = 0; i < 4; ++i) {
      f32x4 v;
      v.x = T[kq + i * 4 + 0][bl];
      v.y = T[kq + i * 4 + 1][bl];
      v.z = T[kq + i * 4 + 2][bl];
      v.w = T[kq + i * 4 + 3][bl];
      *(f32x4*)&out[CPRED_OFF + (size_t)(b0 + bl) * 64 + kq + i * 4] = v;
      *(f32x4*)&out[CINT_OFF + (size_t)(b0 + bl) * 64 + kq + i * 4] = v;
    }
  }
}

extern "C" void kernel_launch(void* const* d_in, const int* in_sizes, int n_in,
                              void* d_out, int out_size, void* d_ws, size_t ws_size,
                              hipStream_t stream) {
  (void)in_sizes; (void)n_in; (void)out_size; (void)ws_size;
  const float* x  = (const float*)d_in[0];
  const float* We = (const float*)d_in[1];
  const float* be = (const float*)d_in[2];
  const float* Wc = (const float*)d_in[3];
  const float* bc = (const float*)d_in[4];
  const float* wp = (const float*)d_in[5];
  const float* bp = (const float*)d_in[6];
  float* out = (float*)d_out;

  // ws layout: We_bf16 (512KB) | Wc_bf16 (4MB) | emb_bf16 (2MB) | ws_pred (2MB f32)
  short* we_bf  = (short*)d_ws;
  short* wc_bf  = we_bf + 262144;
  short* emb_bf = wc_bf + 2097152;
  float* ws_pred = (float*)(emb_bf + 1048576);

  conv2_kernel<<<2304, 256, 0, stream>>>(We, we_bf, 65536, Wc, wc_bf, 524288);
  gemm1_kernel<<<256, 256, 0, stream>>>(x, we_bf, be, out + EMB_OFF, emb_bf);
  gemm2_kernel<<<2048, 512, 0, stream>>>(emb_bf, wc_bf, bc, wp, bp, ws_pred, out);
  pred_tr_kernel<<<128, 256, 0, stream>>>(ws_pred, out);
}

// Round 3
// 124.523 us; speedup vs baseline: 1.1128x; 1.0958x over previous
//
#include <hip/hip_runtime.h>
#include <hip/hip_bf16.h>

// Problem constants
#define IN_F   2048
#define N_CON  64
#define EMB    128
#define BATCH  8192

// Output layout (f32 elements): c_emb | c_pred | c_int | emb
#define CEMB_OFF  0
#define CPRED_OFF 67108864   // 8192*64*128
#define CINT_OFF  67633152   // + 8192*64
#define EMB_OFF   68157440   // + 8192*64

typedef __attribute__((ext_vector_type(4))) float f32x4;
typedef __attribute__((ext_vector_type(8))) short short8;
typedef __attribute__((ext_vector_type(4))) short short4v;

#define MFMA16(A,B,C) __builtin_amdgcn_mfma_f32_16x16x32_bf16((A),(B),(C),0,0,0)

__device__ __forceinline__ short f2bf(float f) {
  unsigned u = __float_as_uint(f);
  u += 0x7FFFu + ((u >> 16) & 1u);   // round-to-nearest-even
  return (short)(u >> 16);
}

__device__ __forceinline__ void gload_lds16(const void* g, void* l) {
  __builtin_amdgcn_global_load_lds(
      (const __attribute__((address_space(1))) unsigned*)g,
      (__attribute__((address_space(3))) unsigned*)l, 16, 0, 0);
}

// ---------------- kernel 0: f32 -> bf16 convert (We + Wc merged) ----------------
__global__ void conv2_kernel(const float* __restrict__ a, short* __restrict__ da, int n4a,
                             const float* __restrict__ b, short* __restrict__ db, int n4b) {
  int i = blockIdx.x * blockDim.x + threadIdx.x;
  const float* s; short* d; int j;
  if (i < n4a)            { s = a; d = da; j = i; }
  else if (i < n4a + n4b) { s = b; d = db; j = i - n4a; }
  else return;
  f32x4 v = *(const f32x4*)(s + (size_t)j * 4);
  short4v o;
  o.x = f2bf(v.x); o.y = f2bf(v.y); o.z = f2bf(v.z); o.w = f2bf(v.w);
  *(short4v*)(d + (size_t)j * 4) = o;
}

// ---------------- kernel 1: emb = leaky(x @ We^T + be) ----------------
// BM=16, grid 512, 256 threads (4 waves), LDS 36 KB -> 4 blocks/CU.
// Wave nw owns cols nw*32..nw*32+31 (nf=2), all 16 rows (mf=1).
__global__ __launch_bounds__(256, 4)
void gemm1_kernel(const float* __restrict__ x,
                  const short* __restrict__ we_bf,   // [128][2048] bf16
                  const float* __restrict__ be,
                  float* __restrict__ out_emb,       // [8192][128] f32
                  short* __restrict__ emb_bf) {      // [8192][128] bf16
  __shared__ short As[16 * 128];    // 4 KB, XOR-swizzled
  __shared__ short Bs[128 * 128];   // 32 KB, XOR-swizzled

  const int t = threadIdx.x;
  const int w = t >> 6, l = t & 63;
  const int row0 = blockIdx.x * 16;

  f32x4 acc[2];
  acc[0] = (f32x4){0.f, 0.f, 0.f, 0.f};
  acc[1] = (f32x4){0.f, 0.f, 0.f, 0.f};

  // A staging: thread t -> row t>>4 (0..15), 8-elem segment t&15
  const int ar = t >> 4;
  const int aseg = t & 15;
  const float* xrow = x + (size_t)(row0 + ar) * IN_F + aseg * 8;
  short* adst = &As[ar * 128 + ((aseg * 8) ^ ((ar & 7) << 3))];

  // B staging (global_load_lds, pre-swizzled source)
  const int brl = t >> 4;
  const int bseg = l & 15;

  for (int kt = 0; kt < 16; ++kt) {
    const int k0 = kt * 128;
    // stage A: f32 -> bf16 through regs, swizzled ds_write (8 elems/thread)
    {
      f32x4 v0 = *(const f32x4*)(xrow + k0);
      f32x4 v1 = *(const f32x4*)(xrow + k0 + 4);
      short8 o;
      o[0] = f2bf(v0.x); o[1] = f2bf(v0.y); o[2] = f2bf(v0.z); o[3] = f2bf(v0.w);
      o[4] = f2bf(v1.x); o[5] = f2bf(v1.y); o[6] = f2bf(v1.z); o[7] = f2bf(v1.w);
      *(short8*)adst = o;
    }
    // stage B: 8 issues x (256 thr * 16B) = 32 KB
#pragma unroll
    for (int i = 0; i < 8; ++i) {
      int n = i * 16 + brl;
      gload_lds16(we_bf + (size_t)n * IN_F + k0 + ((bseg ^ (n & 7)) * 8),
                  &Bs[i * 2048 + w * 512]);
    }
    __syncthreads();
#pragma unroll
    for (int ks = 0; ks < 4; ++ks) {
      int kcol = ks * 32 + ((l >> 4) << 3);
      int r0 = l & 15;
      short8 a = *(const short8*)&As[r0 * 128 + (kcol ^ ((r0 & 7) << 3))];
      int n0 = w * 32 + (l & 15), n1 = n0 + 16;
      short8 b0 = *(const short8*)&Bs[n0 * 128 + (kcol ^ ((n0 & 7) << 3))];
      short8 b1 = *(const short8*)&Bs[n1 * 128 + (kcol ^ ((n1 & 7) << 3))];
      acc[0] = MFMA16(a, b0, acc[0]);
      acc[1] = MFMA16(a, b1, acc[1]);
    }
    __syncthreads();
  }

  // epilogue: + be, leaky, store f32 + bf16
#pragma unroll
  for (int nf = 0; nf < 2; ++nf) {
    int e = w * 32 + nf * 16 + (l & 15);
    float bev = be[e];
#pragma unroll
    for (int r = 0; r < 4; ++r) {
      int b = row0 + ((l >> 4) << 2) + r;
      float v = acc[nf][r] + bev;
      v = v >= 0.f ? v : 0.01f * v;
      out_emb[(size_t)b * EMB + e] = v;
      emb_bf[(size_t)b * EMB + e] = f2bf(v);
    }
  }
}

// ---------------- kernel 2: fused context/gate/c_emb ----------------
// Grid 1024 = 16 m-chunks x 64 concepts. Block = 256 thr (4 waves).
// B (Wc[kc], 64 KB) staged ONCE, then 8 m-iters of 64 rows (A = 16 KB).
// LDS exactly 80 KB -> 2 blocks/CU. Wave nw owns rows nw*16..+16, ALL 256
// cols -> wp-dot reduction stays in-wave (shfl over 16 lanes), no extra LDS.
__global__ __launch_bounds__(256, 2)
void gemm2_kernel(const short* __restrict__ emb_bf,  // [8192][128] bf16
                  const short* __restrict__ wc_bf,   // [64][256][128] bf16
                  const float* __restrict__ bc,      // [64][256]
                  const float* __restrict__ wp,      // [256]
                  const float* __restrict__ bp,      // [1]
                  float* __restrict__ ws_pred,       // [64][8192]
                  float* __restrict__ out) {
  __shared__ short Bs[256 * 128];   // 64 KB
  __shared__ short As[64 * 128];    // 16 KB

  const int t = threadIdx.x;
  const int w = t >> 6, l = t & 63;
  const int kc = blockIdx.x & 63;
  const int mch = (blockIdx.x >> 6) * 512;

  float wph[16], bcv[16];
#pragma unroll
  for (int nf = 0; nf < 16; ++nf) {
    wph[nf] = wp[nf * 16 + (l & 15)];
    bcv[nf] = bc[kc * 256 + nf * 16 + (l & 15)];
  }
  const float bp0 = bp[0];

  const int rl = t >> 4;
  const int seg = l & 15;

  // stage B once: 16 issues x 4 KB
#pragma unroll
  for (int i = 0; i < 16; ++i) {
    int rB = i * 16 + rl;
    gload_lds16(wc_bf + (size_t)kc * 32768 + (size_t)rB * 128 + ((seg ^ (rB & 7)) * 8),
                &Bs[i * 2048 + w * 512]);
  }
  // stage A(0): 4 issues x 4 KB
#pragma unroll
  for (int i = 0; i < 4; ++i) {
    int rA = i * 16 + rl;
    gload_lds16(emb_bf + (size_t)(mch + rA) * 128 + ((seg ^ (rA & 7)) * 8),
                &As[i * 2048 + w * 512]);
  }

  for (int it = 0; it < 8; ++it) {
    __syncthreads();   // drains vmcnt: A(it) (and B) ready; As free from prev reads

    f32x4 acc[16];
#pragma unroll
    for (int j = 0; j < 16; ++j) acc[j] = (f32x4){0.f, 0.f, 0.f, 0.f};

    const int r0 = w * 16 + (l & 15);
#pragma unroll
    for (int ks = 0; ks < 4; ++ks) {
      int kcol = ks * 32 + ((l >> 4) << 3);
      short8 a = *(const short8*)&As[r0 * 128 + (kcol ^ ((r0 & 7) << 3))];
#pragma unroll
      for (int nf = 0; nf < 16; ++nf) {
        int n = nf * 16 + (l & 15);
        short8 b = *(const short8*)&Bs[n * 128 + (kcol ^ ((n & 7) << 3))];
        acc[nf] = MFMA16(a, b, acc[nf]);
      }
    }
    __syncthreads();   // all As reads done -> safe to restage

    if (it < 7) {
#pragma unroll
      for (int i = 0; i < 4; ++i) {
        int rA = i * 16 + rl;
        gload_lds16(emb_bf + (size_t)(mch + (it + 1) * 64 + rA) * 128 + ((seg ^ (rA & 7)) * 8),
                    &As[i * 2048 + w * 512]);
      }
    }

    // epilogue (register-only + shfl): leaky, wp-dot, sigmoid, gate, store
    f32x4 p = (f32x4){0.f, 0.f, 0.f, 0.f};
#pragma unroll
    for (int nf = 0; nf < 16; ++nf) {
#pragma unroll
      for (int r = 0; r < 4; ++r) {
        float v = acc[nf][r] + bcv[nf];
        v = v >= 0.f ? v : 0.01f * v;
        acc[nf][r] = v;
        p[r] += v * wph[nf];
      }
    }
    float g[4];
#pragma unroll
    for (int r = 0; r < 4; ++r) {
      float s = p[r];
      s += __shfl_xor(s, 1);
      s += __shfl_xor(s, 2);
      s += __shfl_xor(s, 4);
      s += __shfl_xor(s, 8);
      g[r] = 1.f / (1.f + __expf(-(s + bp0)));
    }

    const int rowb = mch + it * 64 + w * 16 + ((l >> 4) << 2);
    if ((l & 15) == 0) {
      f32x4 gv; gv.x = g[0]; gv.y = g[1]; gv.z = g[2]; gv.w = g[3];
      *(f32x4*)&ws_pred[(size_t)kc * 8192 + rowb] = gv;
    }
#pragma unroll
    for (int r = 0; r < 4; ++r) {
      int brow = rowb + r;
      float gg = g[r];
#pragma unroll
      for (int nf = 0; nf < 8; ++nf) {
        float v = acc[nf][r] * gg + acc[nf + 8][r] * (1.f - gg);
        out[(size_t)brow * 8192 + kc * 128 + nf * 16 + (l & 15)] = v;
      }
    }
  }
}

// ---------------- kernel 3: transpose ws_pred -> c_pred, c_int ----------------
__global__ __launch_bounds__(256)
void pred_tr_kernel(const float* __restrict__ ws_pred, float* __restrict__ out) {
  __shared__ float T[64][65];
  const int t = threadIdx.x;
  const int b0 = blockIdx.x * 64;

  {
    int kc = t >> 2;
    int j0 = (t & 3) * 16;
    const float* src = ws_pred + (size_t)kc * 8192 + b0 + j0;
#pragma unroll
    for (int i = 0; i < 4; ++i) {
      f32x4 v = *(const f32x4*)(src + i * 4);
      T[kc][j0 + i * 4 + 0] = v.x;
      T[kc][j0 + i * 4 + 1] = v.y;
      T[kc][j0 + i * 4 + 2] = v.z;
      T[kc][j0 + i * 4 + 3] = v.w;
    }
  }
  __syncthreads();
  {
    int bl = t & 63;
    int kq = (t >> 6) * 16;
#pragma unroll
    for (int i = 0; i < 4; ++i) {
      f32x4 v;
      v.x = T[kq + i * 4 + 0][bl];
      v.y = T[kq + i * 4 + 1][bl];
      v.z = T[kq + i * 4 + 2][bl];
      v.w = T[kq + i * 4 + 3][bl];
      *(f32x4*)&out[CPRED_OFF + (size_t)(b0 + bl) * 64 + kq + i * 4] = v;
      *(f32x4*)&out[CINT_OFF + (size_t)(b0 + bl) * 64 + kq + i * 4] = v;
    }
  }
}

extern "C" void kernel_launch(void* const* d_in, const int* in_sizes, int n_in,
                              void* d_out, int out_size, void* d_ws, size_t ws_size,
                              hipStream_t stream) {
  (void)in_sizes; (void)n_in; (void)out_size; (void)ws_size;
  const float* x  = (const float*)d_in[0];
  const float* We = (const float*)d_in[1];
  const float* be = (const float*)d_in[2];
  const float* Wc = (const float*)d_in[3];
  const float* bc = (const float*)d_in[4];
  const float* wp = (const float*)d_in[5];
  const float* bp = (const float*)d_in[6];
  float* out = (float*)d_out;

  // ws layout: We_bf16 (512KB) | Wc_bf16 (4MB) | emb_bf16 (2MB) | ws_pred (2MB f32)
  short* we_bf  = (short*)d_ws;
  short* wc_bf  = we_bf + 262144;
  short* emb_bf = wc_bf + 2097152;
  float* ws_pred = (float*)(emb_bf + 1048576);

  conv2_kernel<<<2304, 256, 0, stream>>>(We, we_bf, 65536, Wc, wc_bf, 524288);
  gemm1_kernel<<<512, 256, 0, stream>>>(x, we_bf, be, out + EMB_OFF, emb_bf);
  gemm2_kernel<<<1024, 256, 0, stream>>>(emb_bf, wc_bf, bc, wp, bp, ws_pred, out);
  pred_tr_kernel<<<128, 256, 0, stream>>>(ws_pred, out);
}